// Round 1
// baseline (645.379 us; speedup 1.0000x reference)
//
#include <hip/hip_runtime.h>
#include <math.h>

#define MEM 32768
#define UNITS 128
#define BATCH 256
#define IN_DIM 512
#define ZDIM 512      // 4*UNITS
#define CI_DIM 768    // IN_DIM + UNITS(r) + UNITS(h)

// ---- d_out offsets (floats), reference return order ----
#define OFF_READ   0
#define OFF_MEMORY (OFF_READ + BATCH*UNITS)        // 32768
#define OFF_CWU    (OFF_MEMORY + MEM*UNITS)        // 4227072
#define OFF_CWLU   (OFF_CWU + MEM*BATCH)           // 12615680
#define OFF_CWR    (OFF_CWLU + MEM*BATCH)          // 21004288
#define OFF_CWW    (OFF_CWR + MEM*BATCH)           // 29392896
#define OFF_H      (OFF_CWW + MEM*BATCH)           // 37781504
#define OFF_C      (OFF_H + BATCH*UNITS)           // 37814272

// ---- ws offsets (bytes) ----
#define WS_INVM   0                                // float[MEM]
#define WS_HT     (MEM*4)                          // float[UNITS*BATCH] (scaled h^T)
#define WS_COLMIN (WS_HT + UNITS*BATCH*4)          // u64[BATCH]
#define WS_MINV   (WS_COLMIN + BATCH*8)            // float[BATCH]
#define WS_COUNT  (WS_MINV + BATCH*4)              // int[MEM]

__device__ __forceinline__ float sigf(float x) { return 1.0f / (1.0f + __expf(-x)); }

// ------------------------------------------------------------------
// K1: LSTM cell (4 rows/block), h/c outputs, h-norm, scaled h^T to ws
// ------------------------------------------------------------------
__global__ __launch_bounds__(512) void k_lstm(
    const float* __restrict__ inp, const float* __restrict__ r_tm1,
    const float* __restrict__ h_tm1, const float* __restrict__ c_tm1,
    const float* __restrict__ W, const float* __restrict__ RW,
    const float* __restrict__ bias,
    float* __restrict__ out, float* __restrict__ hT)
{
    __shared__ float ci[4][CI_DIM];
    __shared__ float zl[4][ZDIM];
    __shared__ float part[8];
    const int t = threadIdx.x;
    const int row0 = blockIdx.x * 4;

    for (int i = t; i < 4 * CI_DIM; i += 512) {
        int r = i / CI_DIM, j = i - r * CI_DIM;
        int row = row0 + r;
        float v;
        if (j < IN_DIM)              v = inp[row * IN_DIM + j];
        else if (j < IN_DIM + UNITS) v = r_tm1[row * UNITS + (j - IN_DIM)];
        else                         v = h_tm1[row * UNITS + (j - IN_DIM - UNITS)];
        ci[r][j] = v;
    }
    __syncthreads();

    float b = bias[t];
    float z0 = b, z1 = b, z2 = b, z3 = b;
    for (int k4 = 0; k4 < (IN_DIM + UNITS) / 4; ++k4) {
        float w0 = W[(k4 * 4 + 0) * ZDIM + t];
        float w1 = W[(k4 * 4 + 1) * ZDIM + t];
        float w2 = W[(k4 * 4 + 2) * ZDIM + t];
        float w3 = W[(k4 * 4 + 3) * ZDIM + t];
        float4 a0 = *(const float4*)&ci[0][k4 * 4];
        float4 a1 = *(const float4*)&ci[1][k4 * 4];
        float4 a2 = *(const float4*)&ci[2][k4 * 4];
        float4 a3 = *(const float4*)&ci[3][k4 * 4];
        z0 += a0.x * w0 + a0.y * w1 + a0.z * w2 + a0.w * w3;
        z1 += a1.x * w0 + a1.y * w1 + a1.z * w2 + a1.w * w3;
        z2 += a2.x * w0 + a2.y * w1 + a2.z * w2 + a2.w * w3;
        z3 += a3.x * w0 + a3.y * w1 + a3.z * w2 + a3.w * w3;
    }
    for (int k4 = 0; k4 < UNITS / 4; ++k4) {
        float w0 = RW[(k4 * 4 + 0) * ZDIM + t];
        float w1 = RW[(k4 * 4 + 1) * ZDIM + t];
        float w2 = RW[(k4 * 4 + 2) * ZDIM + t];
        float w3 = RW[(k4 * 4 + 3) * ZDIM + t];
        const int base = IN_DIM + UNITS + k4 * 4;
        float4 a0 = *(const float4*)&ci[0][base];
        float4 a1 = *(const float4*)&ci[1][base];
        float4 a2 = *(const float4*)&ci[2][base];
        float4 a3 = *(const float4*)&ci[3][base];
        z0 += a0.x * w0 + a0.y * w1 + a0.z * w2 + a0.w * w3;
        z1 += a1.x * w0 + a1.y * w1 + a1.z * w2 + a1.w * w3;
        z2 += a2.x * w0 + a2.y * w1 + a2.z * w2 + a2.w * w3;
        z3 += a3.x * w0 + a3.y * w1 + a3.z * w2 + a3.w * w3;
    }
    zl[0][t] = z0; zl[1][t] = z1; zl[2][t] = z2; zl[3][t] = z3;
    __syncthreads();

    const int r = t >> 7, u = t & 127;
    const int row = row0 + r;
    float iv = zl[r][u], fv = zl[r][UNITS + u], gv = zl[r][2 * UNITS + u], ov = zl[r][3 * UNITS + u];
    float ig = sigf(iv), fg = sigf(fv), og = sigf(ov);
    float gt = tanhf(gv);
    float cn = fg * c_tm1[row * UNITS + u] + ig * gt;
    float hn = og * tanhf(cn);
    out[OFF_C + row * UNITS + u] = cn;
    out[OFF_H + row * UNITS + u] = hn;

    float s = hn * hn;
    for (int d = 1; d < 64; d <<= 1) s += __shfl_xor(s, d, 64);
    int wave = t >> 6;
    if ((t & 63) == 0) part[wave] = s;
    __syncthreads();
    float inv = rsqrtf(fmaxf(part[2 * r] + part[2 * r + 1], 1e-12f));
    hT[u * BATCH + row] = hn * inv;
}

// ------------------------------------------------------------------
// K2: m_tm1 row inverse L2 norms
// ------------------------------------------------------------------
__global__ __launch_bounds__(256) void k_mnorm(const float* __restrict__ m,
                                               float* __restrict__ invm)
{
    const int wid = (blockIdx.x * 256 + threadIdx.x) >> 6; // global wave id
    const int lane = threadIdx.x & 63;
    for (int r = 0; r < 4; ++r) {
        int row = wid * 4 + r;
        float2 v = *(const float2*)&m[row * UNITS + lane * 2];
        float s = v.x * v.x + v.y * v.y;
        for (int d = 1; d < 64; d <<= 1) s += __shfl_xor(s, d, 64);
        if (lane == 0) invm[row] = rsqrtf(fmaxf(s, 1e-12f));
    }
}

// ------------------------------------------------------------------
// K3: cosine sim + softmax + c_wr/c_ww/c_wu + per-column min tracking
// 32 m-rows per block, 128 threads; thread t owns b=t and b=t+128
// ------------------------------------------------------------------
#define MT 32
__global__ __launch_bounds__(128, 4) void k_cos_softmax(
    const float* __restrict__ m, const float* __restrict__ invm,
    const float* __restrict__ hT,
    const float* __restrict__ cwr_tm1, const float* __restrict__ cwlu_tm1,
    const float* __restrict__ cwu_tm1, const float* __restrict__ wgp,
    float* __restrict__ out, unsigned long long* __restrict__ colmin)
{
    __shared__ float smem[MT * 260];            // union: mT[128][36] | cos[32][260]
    __shared__ unsigned long long wmin[2 * BATCH];
    const int t = threadIdx.x;
    const int m0 = blockIdx.x * MT;

    // stage mT[u][ml] = m[(m0+ml)][u] * invm[m0+ml], stride 36 floats
    for (int i = t; i < MT * UNITS / 4; i += 128) {
        int flat = i * 4;
        int ml = flat >> 7;
        int u = flat & 127;
        float4 v = *(const float4*)&m[(m0 + ml) * UNITS + u];
        float sc = invm[m0 + ml];
        smem[(u + 0) * 36 + ml] = v.x * sc;
        smem[(u + 1) * 36 + ml] = v.y * sc;
        smem[(u + 2) * 36 + ml] = v.z * sc;
        smem[(u + 3) * 36 + ml] = v.w * sc;
    }
    __syncthreads();

    float accL[MT], accH[MT];
#pragma unroll
    for (int i = 0; i < MT; ++i) { accL[i] = 0.f; accH[i] = 0.f; }

    for (int u = 0; u < UNITS; ++u) {
        float hl = hT[u * BATCH + t];
        float hh = hT[u * BATCH + t + 128];
#pragma unroll
        for (int m4 = 0; m4 < MT / 4; ++m4) {
            float4 mv = *(const float4*)&smem[u * 36 + m4 * 4];
            accL[m4 * 4 + 0] += mv.x * hl;  accH[m4 * 4 + 0] += mv.x * hh;
            accL[m4 * 4 + 1] += mv.y * hl;  accH[m4 * 4 + 1] += mv.y * hh;
            accL[m4 * 4 + 2] += mv.z * hl;  accH[m4 * 4 + 2] += mv.z * hh;
            accL[m4 * 4 + 3] += mv.w * hl;  accH[m4 * 4 + 3] += mv.w * hh;
        }
    }
    __syncthreads();   // done reading mT

#pragma unroll
    for (int ml = 0; ml < MT; ++ml) {
        smem[ml * 260 + t] = accL[ml];
        smem[ml * 260 + t + 128] = accH[ml];
    }
    __syncthreads();

    const float wg = sigf(wgp[0]);
    const float wgc = 1.0f - wg;
    const int wave = t >> 6, lane = t & 63;
    unsigned long long mk0 = ~0ULL, mk1 = ~0ULL, mk2 = ~0ULL, mk3 = ~0ULL;

    for (int i = 0; i < 16; ++i) {
        int ml = wave * 16 + i;
        int row = m0 + ml;
        float4 v = *(const float4*)&smem[ml * 260 + lane * 4];
        float mx = fmaxf(fmaxf(v.x, v.y), fmaxf(v.z, v.w));
        for (int d = 1; d < 64; d <<= 1) mx = fmaxf(mx, __shfl_xor(mx, d, 64));
        float4 e;
        e.x = __expf(v.x - mx); e.y = __expf(v.y - mx);
        e.z = __expf(v.z - mx); e.w = __expf(v.w - mx);
        float s = e.x + e.y + e.z + e.w;
        for (int d = 1; d < 64; d <<= 1) s += __shfl_xor(s, d, 64);
        float is = 1.0f / s;
        float4 wr; wr.x = e.x * is; wr.y = e.y * is; wr.z = e.z * is; wr.w = e.w * is;
        *(float4*)&out[OFF_CWR + row * BATCH + lane * 4] = wr;

        float4 pr = *(const float4*)&cwr_tm1[row * BATCH + lane * 4];
        float4 pl = *(const float4*)&cwlu_tm1[row * BATCH + lane * 4];
        float4 ww;
        ww.x = wg * pr.x + wgc + pl.x; ww.y = wg * pr.y + wgc + pl.y;
        ww.z = wg * pr.z + wgc + pl.z; ww.w = wg * pr.w + wgc + pl.w;
        *(float4*)&out[OFF_CWW + row * BATCH + lane * 4] = ww;

        float4 pu = *(const float4*)&cwu_tm1[row * BATCH + lane * 4];
        float4 wu;
        wu.x = 0.95f * pu.x + wr.x + ww.x; wu.y = 0.95f * pu.y + wr.y + ww.y;
        wu.z = 0.95f * pu.z + wr.z + ww.z; wu.w = 0.95f * pu.w + wr.w + ww.w;
        *(float4*)&out[OFF_CWU + row * BATCH + lane * 4] = wu;

        // pack (bits<<32)|(MEM-1-row): min-key => min value, largest index on ties
        unsigned idxc = (unsigned)(MEM - 1 - row);
        unsigned long long k;
        k = ((unsigned long long)__float_as_uint(wu.x) << 32) | idxc; if (k < mk0) mk0 = k;
        k = ((unsigned long long)__float_as_uint(wu.y) << 32) | idxc; if (k < mk1) mk1 = k;
        k = ((unsigned long long)__float_as_uint(wu.z) << 32) | idxc; if (k < mk2) mk2 = k;
        k = ((unsigned long long)__float_as_uint(wu.w) << 32) | idxc; if (k < mk3) mk3 = k;
    }
    wmin[wave * BATCH + lane * 4 + 0] = mk0;
    wmin[wave * BATCH + lane * 4 + 1] = mk1;
    wmin[wave * BATCH + lane * 4 + 2] = mk2;
    wmin[wave * BATCH + lane * 4 + 3] = mk3;
    __syncthreads();
    for (int b = t; b < BATCH; b += 128) {
        unsigned long long a = wmin[b], c = wmin[BATCH + b];
        unsigned long long k = a < c ? a : c;
        if (k < colmin[b]) atomicMin(&colmin[b], k);   // peek to skip most atomics
    }
}

// ------------------------------------------------------------------
// K4: decode column minima -> minv + argmin counts
// ------------------------------------------------------------------
__global__ void k_decode(const unsigned long long* __restrict__ colmin,
                         float* __restrict__ minv, int* __restrict__ count)
{
    int t = threadIdx.x;
    unsigned long long k = colmin[t];
    minv[t] = __uint_as_float((unsigned)(k >> 32));
    int idx = MEM - 1 - (int)(unsigned)(k & 0xffffffffu);
    atomicAdd(&count[idx], 1);
}

// ------------------------------------------------------------------
// K5: c_wlu = (c_wu <= minv[b])
// ------------------------------------------------------------------
__global__ __launch_bounds__(256) void k_wlu(const float* __restrict__ cwu,
                                             const float* __restrict__ minv,
                                             float* __restrict__ wlu)
{
    int i = blockIdx.x * 256 + threadIdx.x;   // float4 index
    float4 v = *(const float4*)&cwu[i * 4];
    float4 mv = *(const float4*)&minv[(i & 63) * 4];
    float4 r;
    r.x = (v.x <= mv.x) ? 1.0f : 0.0f;
    r.y = (v.y <= mv.y) ? 1.0f : 0.0f;
    r.z = (v.z <= mv.z) ? 1.0f : 0.0f;
    r.w = (v.w <= mv.w) ? 1.0f : 0.0f;
    *(float4*)&wlu[i * 4] = r;
}

// ------------------------------------------------------------------
// K6: memory = c_ww @ h + (BATCH - count[m]) * m_tm1
// 32 m-rows/block, 128 threads (u). c_ww addresses are wave-uniform -> s_load.
// ------------------------------------------------------------------
__global__ __launch_bounds__(128, 4) void k_memory(
    const float* __restrict__ cww, const float* __restrict__ h,
    const float* __restrict__ m, const int* __restrict__ count,
    float* __restrict__ mem_out)
{
    const int t = threadIdx.x;
    const int m0 = blockIdx.x * 32;
    float acc[32];
#pragma unroll
    for (int i = 0; i < 32; ++i) acc[i] = 0.f;

    for (int b4 = 0; b4 < BATCH / 4; ++b4) {
        float h0 = h[(4 * b4 + 0) * UNITS + t];
        float h1 = h[(4 * b4 + 1) * UNITS + t];
        float h2 = h[(4 * b4 + 2) * UNITS + t];
        float h3 = h[(4 * b4 + 3) * UNITS + t];
#pragma unroll
        for (int ml = 0; ml < 32; ++ml) {
            float4 c = *(const float4*)&cww[(m0 + ml) * BATCH + 4 * b4];
            acc[ml] += c.x * h0 + c.y * h1 + c.z * h2 + c.w * h3;
        }
    }
#pragma unroll
    for (int ml = 0; ml < 32; ++ml) {
        int row = m0 + ml;
        float sc = (float)(BATCH - count[row]);
        mem_out[row * UNITS + t] = acc[ml] + sc * m[row * UNITS + t];
    }
}

// ------------------------------------------------------------------
// K7: read = c_wr^T @ m_tm1, split-K with f32 atomics
// blockIdx: low 4 bits = b-tile(16 cols), high bits = K-chunk of 512 rows
// ------------------------------------------------------------------
__global__ __launch_bounds__(128, 4) void k_read(
    const float* __restrict__ cwr, const float* __restrict__ m,
    float* __restrict__ read_out)
{
    const int t = threadIdx.x;
    const int b0 = (blockIdx.x & 15) * 16;
    const int mbase = (blockIdx.x >> 4) * 512;
    float acc[16];
#pragma unroll
    for (int i = 0; i < 16; ++i) acc[i] = 0.f;

    for (int mm = 0; mm < 512; ++mm) {
        int row = mbase + mm;
        float mv = m[row * UNITS + t];
        float4 c0 = *(const float4*)&cwr[row * BATCH + b0 + 0];
        float4 c1 = *(const float4*)&cwr[row * BATCH + b0 + 4];
        float4 c2 = *(const float4*)&cwr[row * BATCH + b0 + 8];
        float4 c3 = *(const float4*)&cwr[row * BATCH + b0 + 12];
        acc[0]  += c0.x * mv; acc[1]  += c0.y * mv; acc[2]  += c0.z * mv; acc[3]  += c0.w * mv;
        acc[4]  += c1.x * mv; acc[5]  += c1.y * mv; acc[6]  += c1.z * mv; acc[7]  += c1.w * mv;
        acc[8]  += c2.x * mv; acc[9]  += c2.y * mv; acc[10] += c2.z * mv; acc[11] += c2.w * mv;
        acc[12] += c3.x * mv; acc[13] += c3.y * mv; acc[14] += c3.z * mv; acc[15] += c3.w * mv;
    }
#pragma unroll
    for (int j = 0; j < 16; ++j)
        atomicAdd(&read_out[(b0 + j) * UNITS + t], acc[j]);
}

// ------------------------------------------------------------------
extern "C" void kernel_launch(void* const* d_in, const int* in_sizes, int n_in,
                              void* d_out, int out_size, void* d_ws, size_t ws_size,
                              hipStream_t stream)
{
    (void)in_sizes; (void)n_in; (void)out_size; (void)ws_size;
    const float* inp      = (const float*)d_in[0];
    const float* r_tm1    = (const float*)d_in[1];
    const float* m_tm1    = (const float*)d_in[2];
    const float* cwu_tm1  = (const float*)d_in[3];
    const float* cwlu_tm1 = (const float*)d_in[4];
    const float* cwr_tm1  = (const float*)d_in[5];
    // d_in[6] = c_ww_tm1: unused by the reference
    const float* h_tm1    = (const float*)d_in[7];
    const float* c_tm1    = (const float*)d_in[8];
    const float* W        = (const float*)d_in[9];
    const float* RW       = (const float*)d_in[10];
    const float* bias     = (const float*)d_in[11];
    const float* wgp      = (const float*)d_in[12];

    float* out = (float*)d_out;
    char* ws = (char*)d_ws;
    float* invm = (float*)(ws + WS_INVM);
    float* hT   = (float*)(ws + WS_HT);
    unsigned long long* colmin = (unsigned long long*)(ws + WS_COLMIN);
    float* minv = (float*)(ws + WS_MINV);
    int* count  = (int*)(ws + WS_COUNT);

    hipMemsetAsync(out + OFF_READ, 0, BATCH * UNITS * sizeof(float), stream);
    hipMemsetAsync(colmin, 0xFF, BATCH * sizeof(unsigned long long), stream);
    hipMemsetAsync(count, 0, MEM * sizeof(int), stream);

    k_lstm<<<BATCH / 4, 512, 0, stream>>>(inp, r_tm1, h_tm1, c_tm1, W, RW, bias, out, hT);
    k_mnorm<<<MEM / 16, 256, 0, stream>>>(m_tm1, invm);
    k_cos_softmax<<<MEM / MT, 128, 0, stream>>>(m_tm1, invm, hT, cwr_tm1, cwlu_tm1,
                                                cwu_tm1, wgp, out, colmin);
    k_decode<<<1, BATCH, 0, stream>>>(colmin, minv, count);
    k_wlu<<<(MEM * BATCH / 4) / 256, 256, 0, stream>>>(out + OFF_CWU, minv, out + OFF_CWLU);
    k_memory<<<MEM / 32, 128, 0, stream>>>(out + OFF_CWW, out + OFF_H, m_tm1, count,
                                           out + OFF_MEMORY);
    k_read<<<16 * (MEM / 512), 128, 0, stream>>>(out + OFF_CWR, m_tm1, out + OFF_READ);
}

// Round 2
// 493.305 us; speedup vs baseline: 1.3083x; 1.3083x over previous
//
#include <hip/hip_runtime.h>
#include <math.h>

#define MEM 32768
#define UNITS 128
#define BATCH 256
#define IN_DIM 512
#define ZDIM 512      // 4*UNITS
#define CI_DIM 768    // IN_DIM + UNITS(r) + UNITS(h)

// ---- d_out offsets (floats), reference return order ----
#define OFF_READ   0
#define OFF_MEMORY (OFF_READ + BATCH*UNITS)        // 32768
#define OFF_CWU    (OFF_MEMORY + MEM*UNITS)        // 4227072
#define OFF_CWLU   (OFF_CWU + MEM*BATCH)           // 12615680
#define OFF_CWR    (OFF_CWLU + MEM*BATCH)          // 21004288
#define OFF_CWW    (OFF_CWR + MEM*BATCH)           // 29392896
#define OFF_H      (OFF_CWW + MEM*BATCH)           // 37781504
#define OFF_C      (OFF_H + BATCH*UNITS)           // 37814272

// ---- ws offsets (bytes) ----
#define WS_INVM   0                                // float[MEM]
#define WS_HT     (MEM*4)                          // float[UNITS*BATCH] (scaled h^T)
#define WS_COLMIN (WS_HT + UNITS*BATCH*4)          // u64[BATCH]
#define WS_MINV   (WS_COLMIN + BATCH*8)            // float[BATCH]
#define WS_COUNT  (WS_MINV + BATCH*4)              // int[MEM]
#define WS_PART   (512*1024)                       // float[64][BATCH][UNITS] split-K partials
#define PART_BYTES (64*BATCH*UNITS*4)              // 8 MB

__device__ __forceinline__ float sigf(float x) { return 1.0f / (1.0f + __expf(-x)); }

// ------------------------------------------------------------------
// K1: LSTM cell (4 rows/block), h/c outputs, h-norm, scaled h^T to ws
// ------------------------------------------------------------------
__global__ __launch_bounds__(512) void k_lstm(
    const float* __restrict__ inp, const float* __restrict__ r_tm1,
    const float* __restrict__ h_tm1, const float* __restrict__ c_tm1,
    const float* __restrict__ W, const float* __restrict__ RW,
    const float* __restrict__ bias,
    float* __restrict__ out, float* __restrict__ hT)
{
    __shared__ float ci[4][CI_DIM];
    __shared__ float zl[4][ZDIM];
    __shared__ float part[8];
    const int t = threadIdx.x;
    const int row0 = blockIdx.x * 4;

    for (int i = t; i < 4 * CI_DIM; i += 512) {
        int r = i / CI_DIM, j = i - r * CI_DIM;
        int row = row0 + r;
        float v;
        if (j < IN_DIM)              v = inp[row * IN_DIM + j];
        else if (j < IN_DIM + UNITS) v = r_tm1[row * UNITS + (j - IN_DIM)];
        else                         v = h_tm1[row * UNITS + (j - IN_DIM - UNITS)];
        ci[r][j] = v;
    }
    __syncthreads();

    float b = bias[t];
    float z0 = b, z1 = b, z2 = b, z3 = b;
    for (int k4 = 0; k4 < (IN_DIM + UNITS) / 4; ++k4) {
        float w0 = W[(k4 * 4 + 0) * ZDIM + t];
        float w1 = W[(k4 * 4 + 1) * ZDIM + t];
        float w2 = W[(k4 * 4 + 2) * ZDIM + t];
        float w3 = W[(k4 * 4 + 3) * ZDIM + t];
        float4 a0 = *(const float4*)&ci[0][k4 * 4];
        float4 a1 = *(const float4*)&ci[1][k4 * 4];
        float4 a2 = *(const float4*)&ci[2][k4 * 4];
        float4 a3 = *(const float4*)&ci[3][k4 * 4];
        z0 += a0.x * w0 + a0.y * w1 + a0.z * w2 + a0.w * w3;
        z1 += a1.x * w0 + a1.y * w1 + a1.z * w2 + a1.w * w3;
        z2 += a2.x * w0 + a2.y * w1 + a2.z * w2 + a2.w * w3;
        z3 += a3.x * w0 + a3.y * w1 + a3.z * w2 + a3.w * w3;
    }
    for (int k4 = 0; k4 < UNITS / 4; ++k4) {
        float w0 = RW[(k4 * 4 + 0) * ZDIM + t];
        float w1 = RW[(k4 * 4 + 1) * ZDIM + t];
        float w2 = RW[(k4 * 4 + 2) * ZDIM + t];
        float w3 = RW[(k4 * 4 + 3) * ZDIM + t];
        const int base = IN_DIM + UNITS + k4 * 4;
        float4 a0 = *(const float4*)&ci[0][base];
        float4 a1 = *(const float4*)&ci[1][base];
        float4 a2 = *(const float4*)&ci[2][base];
        float4 a3 = *(const float4*)&ci[3][base];
        z0 += a0.x * w0 + a0.y * w1 + a0.z * w2 + a0.w * w3;
        z1 += a1.x * w0 + a1.y * w1 + a1.z * w2 + a1.w * w3;
        z2 += a2.x * w0 + a2.y * w1 + a2.z * w2 + a2.w * w3;
        z3 += a3.x * w0 + a3.y * w1 + a3.z * w2 + a3.w * w3;
    }
    zl[0][t] = z0; zl[1][t] = z1; zl[2][t] = z2; zl[3][t] = z3;
    __syncthreads();

    const int r = t >> 7, u = t & 127;
    const int row = row0 + r;
    float iv = zl[r][u], fv = zl[r][UNITS + u], gv = zl[r][2 * UNITS + u], ov = zl[r][3 * UNITS + u];
    float ig = sigf(iv), fg = sigf(fv), og = sigf(ov);
    float gt = tanhf(gv);
    float cn = fg * c_tm1[row * UNITS + u] + ig * gt;
    float hn = og * tanhf(cn);
    out[OFF_C + row * UNITS + u] = cn;
    out[OFF_H + row * UNITS + u] = hn;

    float s = hn * hn;
    for (int d = 1; d < 64; d <<= 1) s += __shfl_xor(s, d, 64);
    int wave = t >> 6;
    if ((t & 63) == 0) part[wave] = s;
    __syncthreads();
    float inv = rsqrtf(fmaxf(part[2 * r] + part[2 * r + 1], 1e-12f));
    hT[u * BATCH + row] = hn * inv;
}

// ------------------------------------------------------------------
// K2: m_tm1 row inverse L2 norms
// ------------------------------------------------------------------
__global__ __launch_bounds__(256) void k_mnorm(const float* __restrict__ m,
                                               float* __restrict__ invm)
{
    const int wid = (blockIdx.x * 256 + threadIdx.x) >> 6; // global wave id
    const int lane = threadIdx.x & 63;
    for (int r = 0; r < 4; ++r) {
        int row = wid * 4 + r;
        float2 v = *(const float2*)&m[row * UNITS + lane * 2];
        float s = v.x * v.x + v.y * v.y;
        for (int d = 1; d < 64; d <<= 1) s += __shfl_xor(s, d, 64);
        if (lane == 0) invm[row] = rsqrtf(fmaxf(s, 1e-12f));
    }
}

// ------------------------------------------------------------------
// K3: cosine sim + softmax + c_wr/c_ww/c_wu + per-column min tracking
// 32 m-rows per block, 128 threads; thread t owns b=t and b=t+128
// ------------------------------------------------------------------
#define MT 32
__global__ __launch_bounds__(128, 4) void k_cos_softmax(
    const float* __restrict__ m, const float* __restrict__ invm,
    const float* __restrict__ hT,
    const float* __restrict__ cwr_tm1, const float* __restrict__ cwlu_tm1,
    const float* __restrict__ cwu_tm1, const float* __restrict__ wgp,
    float* __restrict__ out, unsigned long long* __restrict__ colmin)
{
    __shared__ float smem[MT * 260];            // union: mT[128][36] | cos[32][260]
    __shared__ unsigned long long wmin[2 * BATCH];
    const int t = threadIdx.x;
    const int m0 = blockIdx.x * MT;

    // stage mT[u][ml] = m[(m0+ml)][u] * invm[m0+ml], stride 36 floats
    for (int i = t; i < MT * UNITS / 4; i += 128) {
        int flat = i * 4;
        int ml = flat >> 7;
        int u = flat & 127;
        float4 v = *(const float4*)&m[(m0 + ml) * UNITS + u];
        float sc = invm[m0 + ml];
        smem[(u + 0) * 36 + ml] = v.x * sc;
        smem[(u + 1) * 36 + ml] = v.y * sc;
        smem[(u + 2) * 36 + ml] = v.z * sc;
        smem[(u + 3) * 36 + ml] = v.w * sc;
    }
    __syncthreads();

    float accL[MT], accH[MT];
#pragma unroll
    for (int i = 0; i < MT; ++i) { accL[i] = 0.f; accH[i] = 0.f; }

    for (int u = 0; u < UNITS; ++u) {
        float hl = hT[u * BATCH + t];
        float hh = hT[u * BATCH + t + 128];
#pragma unroll
        for (int m4 = 0; m4 < MT / 4; ++m4) {
            float4 mv = *(const float4*)&smem[u * 36 + m4 * 4];
            accL[m4 * 4 + 0] += mv.x * hl;  accH[m4 * 4 + 0] += mv.x * hh;
            accL[m4 * 4 + 1] += mv.y * hl;  accH[m4 * 4 + 1] += mv.y * hh;
            accL[m4 * 4 + 2] += mv.z * hl;  accH[m4 * 4 + 2] += mv.z * hh;
            accL[m4 * 4 + 3] += mv.w * hl;  accH[m4 * 4 + 3] += mv.w * hh;
        }
    }
    __syncthreads();   // done reading mT

#pragma unroll
    for (int ml = 0; ml < MT; ++ml) {
        smem[ml * 260 + t] = accL[ml];
        smem[ml * 260 + t + 128] = accH[ml];
    }
    __syncthreads();

    const float wg = sigf(wgp[0]);
    const float wgc = 1.0f - wg;
    const int wave = t >> 6, lane = t & 63;
    unsigned long long mk0 = ~0ULL, mk1 = ~0ULL, mk2 = ~0ULL, mk3 = ~0ULL;

    for (int i = 0; i < 16; ++i) {
        int ml = wave * 16 + i;
        int row = m0 + ml;
        float4 v = *(const float4*)&smem[ml * 260 + lane * 4];
        float mx = fmaxf(fmaxf(v.x, v.y), fmaxf(v.z, v.w));
        for (int d = 1; d < 64; d <<= 1) mx = fmaxf(mx, __shfl_xor(mx, d, 64));
        float4 e;
        e.x = __expf(v.x - mx); e.y = __expf(v.y - mx);
        e.z = __expf(v.z - mx); e.w = __expf(v.w - mx);
        float s = e.x + e.y + e.z + e.w;
        for (int d = 1; d < 64; d <<= 1) s += __shfl_xor(s, d, 64);
        float is = 1.0f / s;
        float4 wr; wr.x = e.x * is; wr.y = e.y * is; wr.z = e.z * is; wr.w = e.w * is;
        *(float4*)&out[OFF_CWR + row * BATCH + lane * 4] = wr;

        float4 pr = *(const float4*)&cwr_tm1[row * BATCH + lane * 4];
        float4 pl = *(const float4*)&cwlu_tm1[row * BATCH + lane * 4];
        float4 ww;
        ww.x = wg * pr.x + wgc + pl.x; ww.y = wg * pr.y + wgc + pl.y;
        ww.z = wg * pr.z + wgc + pl.z; ww.w = wg * pr.w + wgc + pl.w;
        *(float4*)&out[OFF_CWW + row * BATCH + lane * 4] = ww;

        float4 pu = *(const float4*)&cwu_tm1[row * BATCH + lane * 4];
        float4 wu;
        wu.x = 0.95f * pu.x + wr.x + ww.x; wu.y = 0.95f * pu.y + wr.y + ww.y;
        wu.z = 0.95f * pu.z + wr.z + ww.z; wu.w = 0.95f * pu.w + wr.w + ww.w;
        *(float4*)&out[OFF_CWU + row * BATCH + lane * 4] = wu;

        // pack (bits<<32)|(MEM-1-row): min-key => min value, largest index on ties
        unsigned idxc = (unsigned)(MEM - 1 - row);
        unsigned long long k;
        k = ((unsigned long long)__float_as_uint(wu.x) << 32) | idxc; if (k < mk0) mk0 = k;
        k = ((unsigned long long)__float_as_uint(wu.y) << 32) | idxc; if (k < mk1) mk1 = k;
        k = ((unsigned long long)__float_as_uint(wu.z) << 32) | idxc; if (k < mk2) mk2 = k;
        k = ((unsigned long long)__float_as_uint(wu.w) << 32) | idxc; if (k < mk3) mk3 = k;
    }
    wmin[wave * BATCH + lane * 4 + 0] = mk0;
    wmin[wave * BATCH + lane * 4 + 1] = mk1;
    wmin[wave * BATCH + lane * 4 + 2] = mk2;
    wmin[wave * BATCH + lane * 4 + 3] = mk3;
    __syncthreads();
    for (int b = t; b < BATCH; b += 128) {
        unsigned long long a = wmin[b], c = wmin[BATCH + b];
        unsigned long long k = a < c ? a : c;
        if (k < colmin[b]) atomicMin(&colmin[b], k);   // peek to skip most atomics
    }
}

// ------------------------------------------------------------------
// K4: decode column minima -> minv + argmin counts
// ------------------------------------------------------------------
__global__ void k_decode(const unsigned long long* __restrict__ colmin,
                         float* __restrict__ minv, int* __restrict__ count)
{
    int t = threadIdx.x;
    unsigned long long k = colmin[t];
    minv[t] = __uint_as_float((unsigned)(k >> 32));
    int idx = MEM - 1 - (int)(unsigned)(k & 0xffffffffu);
    atomicAdd(&count[idx], 1);
}

// ------------------------------------------------------------------
// K5: c_wlu = (c_wu <= minv[b])
// ------------------------------------------------------------------
__global__ __launch_bounds__(256) void k_wlu(const float* __restrict__ cwu,
                                             const float* __restrict__ minv,
                                             float* __restrict__ wlu)
{
    int i = blockIdx.x * 256 + threadIdx.x;   // float4 index
    float4 v = *(const float4*)&cwu[i * 4];
    float4 mv = *(const float4*)&minv[(i & 63) * 4];
    float4 r;
    r.x = (v.x <= mv.x) ? 1.0f : 0.0f;
    r.y = (v.y <= mv.y) ? 1.0f : 0.0f;
    r.z = (v.z <= mv.z) ? 1.0f : 0.0f;
    r.w = (v.w <= mv.w) ? 1.0f : 0.0f;
    *(float4*)&wlu[i * 4] = r;
}

// ------------------------------------------------------------------
// K6 v2: memory = c_ww @ h + (BATCH - count[m]) * m_tm1
// LDS-tiled GEMM: 64 m-rows x 128 u per block, 256 threads, K-chunks of 32.
// A-tile stored transposed [bb][ml] stride 68 (16B-aligned b128 reads,
// <=4-way conflicts on staging writes only). B-tile [bb][u] stride 128.
// ------------------------------------------------------------------
__global__ __launch_bounds__(256) void k_memory(
    const float* __restrict__ cww, const float* __restrict__ h,
    const float* __restrict__ m, const int* __restrict__ count,
    float* __restrict__ mem_out)
{
    __shared__ float Als[32 * 68];
    __shared__ float Bls[32 * 128];
    const int t = threadIdx.x;
    const int m0 = blockIdx.x * 64;
    const int u4 = (t & 31) * 4;     // u offset
    const int mg = t >> 5;           // 0..7, owns m-rows mg*8..mg*8+7
    float4 acc[8];
#pragma unroll
    for (int i = 0; i < 8; ++i) { acc[i].x = 0.f; acc[i].y = 0.f; acc[i].z = 0.f; acc[i].w = 0.f; }

    for (int b0 = 0; b0 < BATCH; b0 += 32) {
        // stage A: cww[m0+ml][b0+bb] -> Als[bb*68+ml], 512 float4 loads
#pragma unroll
        for (int ii = 0; ii < 2; ++ii) {
            int i = t + ii * 256;
            int ml = i >> 3, bb4 = (i & 7) * 4;
            float4 v = *(const float4*)&cww[(m0 + ml) * BATCH + b0 + bb4];
            Als[(bb4 + 0) * 68 + ml] = v.x;
            Als[(bb4 + 1) * 68 + ml] = v.y;
            Als[(bb4 + 2) * 68 + ml] = v.z;
            Als[(bb4 + 3) * 68 + ml] = v.w;
        }
        // stage B: h[b0+bb][u] -> Bls[bb*128+u], 1024 float4 loads
#pragma unroll
        for (int ii = 0; ii < 4; ++ii) {
            int i = t + ii * 256;
            int bb = i >> 5, uu = (i & 31) * 4;
            *(float4*)&Bls[bb * 128 + uu] = *(const float4*)&h[(b0 + bb) * UNITS + uu];
        }
        __syncthreads();
#pragma unroll 8
        for (int bb = 0; bb < 32; ++bb) {
            float4 bv = *(const float4*)&Bls[bb * 128 + u4];
            float4 av0 = *(const float4*)&Als[bb * 68 + mg * 8];
            float4 av1 = *(const float4*)&Als[bb * 68 + mg * 8 + 4];
            acc[0].x += av0.x * bv.x; acc[0].y += av0.x * bv.y; acc[0].z += av0.x * bv.z; acc[0].w += av0.x * bv.w;
            acc[1].x += av0.y * bv.x; acc[1].y += av0.y * bv.y; acc[1].z += av0.y * bv.z; acc[1].w += av0.y * bv.w;
            acc[2].x += av0.z * bv.x; acc[2].y += av0.z * bv.y; acc[2].z += av0.z * bv.z; acc[2].w += av0.z * bv.w;
            acc[3].x += av0.w * bv.x; acc[3].y += av0.w * bv.y; acc[3].z += av0.w * bv.z; acc[3].w += av0.w * bv.w;
            acc[4].x += av1.x * bv.x; acc[4].y += av1.x * bv.y; acc[4].z += av1.x * bv.z; acc[4].w += av1.x * bv.w;
            acc[5].x += av1.y * bv.x; acc[5].y += av1.y * bv.y; acc[5].z += av1.y * bv.z; acc[5].w += av1.y * bv.w;
            acc[6].x += av1.z * bv.x; acc[6].y += av1.z * bv.y; acc[6].z += av1.z * bv.z; acc[6].w += av1.z * bv.w;
            acc[7].x += av1.w * bv.x; acc[7].y += av1.w * bv.y; acc[7].z += av1.w * bv.z; acc[7].w += av1.w * bv.w;
        }
        __syncthreads();
    }

#pragma unroll
    for (int i = 0; i < 8; ++i) {
        int row = m0 + mg * 8 + i;
        float sc = (float)(BATCH - count[row]);
        float4 mv = *(const float4*)&m[row * UNITS + u4];
        float4 o;
        o.x = acc[i].x + sc * mv.x;
        o.y = acc[i].y + sc * mv.y;
        o.z = acc[i].z + sc * mv.z;
        o.w = acc[i].w + sc * mv.w;
        *(float4*)&mem_out[row * UNITS + u4] = o;
    }
}

// ------------------------------------------------------------------
// K7 v2: read = c_wr^T @ m_tm1, LDS-tiled split-K GEMM.
// Block = (K-chunk c of 512 rows) x (b-tile of 32), 256 threads.
// Thread owns b = bg*4..+3, u = u4..+3 (16 outputs).
// use_part: write partials to ws (no atomics), else atomicAdd fallback.
// ------------------------------------------------------------------
__global__ __launch_bounds__(256) void k_read(
    const float* __restrict__ cwr, const float* __restrict__ m,
    float* __restrict__ dst, int use_part)
{
    __shared__ float Als[32 * 36];    // [mm][b] stride 36 (16B aligned)
    __shared__ float Bls[32 * 128];   // [mm][u]
    const int t = threadIdx.x;
    const int c  = blockIdx.x >> 3;
    const int b0 = (blockIdx.x & 7) * 32;
    const int k0 = c * 512;
    const int u4 = (t & 31) * 4;
    const int bg = t >> 5;
    float4 a0, a1, a2, a3;
    a0.x=0;a0.y=0;a0.z=0;a0.w=0; a1=a0; a2=a0; a3=a0;

    for (int mc = 0; mc < 16; ++mc) {
        const int kb = k0 + mc * 32;
        {   // stage A: cwr[kb+row][b0+j] -> Als[row*36+j], 256 float4 (1/thread)
            int row = t >> 3, j4 = (t & 7) * 4;
            float4 v = *(const float4*)&cwr[(kb + row) * BATCH + b0 + j4];
            *(float4*)&Als[row * 36 + j4] = v;
        }
#pragma unroll
        for (int ii = 0; ii < 4; ++ii) {   // stage B: m[kb+bb][u]
            int i = t + ii * 256;
            int bb = i >> 5, uu = (i & 31) * 4;
            *(float4*)&Bls[bb * 128 + uu] = *(const float4*)&m[(kb + bb) * UNITS + uu];
        }
        __syncthreads();
#pragma unroll 8
        for (int mm = 0; mm < 32; ++mm) {
            float4 av = *(const float4*)&Als[mm * 36 + bg * 4];
            float4 bv = *(const float4*)&Bls[mm * 128 + u4];
            a0.x += av.x * bv.x; a0.y += av.x * bv.y; a0.z += av.x * bv.z; a0.w += av.x * bv.w;
            a1.x += av.y * bv.x; a1.y += av.y * bv.y; a1.z += av.y * bv.z; a1.w += av.y * bv.w;
            a2.x += av.z * bv.x; a2.y += av.z * bv.y; a2.z += av.z * bv.z; a2.w += av.z * bv.w;
            a3.x += av.w * bv.x; a3.y += av.w * bv.y; a3.z += av.w * bv.z; a3.w += av.w * bv.w;
        }
        __syncthreads();
    }

    const int b = b0 + bg * 4;
    if (use_part) {
        float* p = dst + (size_t)c * (BATCH * UNITS);
        *(float4*)&p[(b + 0) * UNITS + u4] = a0;
        *(float4*)&p[(b + 1) * UNITS + u4] = a1;
        *(float4*)&p[(b + 2) * UNITS + u4] = a2;
        *(float4*)&p[(b + 3) * UNITS + u4] = a3;
    } else {
        atomicAdd(&dst[(b + 0) * UNITS + u4 + 0], a0.x); atomicAdd(&dst[(b + 0) * UNITS + u4 + 1], a0.y);
        atomicAdd(&dst[(b + 0) * UNITS + u4 + 2], a0.z); atomicAdd(&dst[(b + 0) * UNITS + u4 + 3], a0.w);
        atomicAdd(&dst[(b + 1) * UNITS + u4 + 0], a1.x); atomicAdd(&dst[(b + 1) * UNITS + u4 + 1], a1.y);
        atomicAdd(&dst[(b + 1) * UNITS + u4 + 2], a1.z); atomicAdd(&dst[(b + 1) * UNITS + u4 + 3], a1.w);
        atomicAdd(&dst[(b + 2) * UNITS + u4 + 0], a2.x); atomicAdd(&dst[(b + 2) * UNITS + u4 + 1], a2.y);
        atomicAdd(&dst[(b + 2) * UNITS + u4 + 2], a2.z); atomicAdd(&dst[(b + 2) * UNITS + u4 + 3], a2.w);
        atomicAdd(&dst[(b + 3) * UNITS + u4 + 0], a3.x); atomicAdd(&dst[(b + 3) * UNITS + u4 + 1], a3.y);
        atomicAdd(&dst[(b + 3) * UNITS + u4 + 2], a3.z); atomicAdd(&dst[(b + 3) * UNITS + u4 + 3], a3.w);
    }
}

// ------------------------------------------------------------------
// K8: reduce split-K partials -> read
// ------------------------------------------------------------------
__global__ __launch_bounds__(256) void k_reduce(const float* __restrict__ part,
                                                float* __restrict__ out)
{
    int i = blockIdx.x * 256 + threadIdx.x;     // 0 .. BATCH*UNITS
    float s = 0.f;
#pragma unroll
    for (int c = 0; c < 64; ++c) s += part[c * (BATCH * UNITS) + i];
    out[i] = s;
}

// ------------------------------------------------------------------
extern "C" void kernel_launch(void* const* d_in, const int* in_sizes, int n_in,
                              void* d_out, int out_size, void* d_ws, size_t ws_size,
                              hipStream_t stream)
{
    (void)in_sizes; (void)n_in; (void)out_size;
    const float* inp      = (const float*)d_in[0];
    const float* r_tm1    = (const float*)d_in[1];
    const float* m_tm1    = (const float*)d_in[2];
    const float* cwu_tm1  = (const float*)d_in[3];
    const float* cwlu_tm1 = (const float*)d_in[4];
    const float* cwr_tm1  = (const float*)d_in[5];
    // d_in[6] = c_ww_tm1: unused by the reference
    const float* h_tm1    = (const float*)d_in[7];
    const float* c_tm1    = (const float*)d_in[8];
    const float* W        = (const float*)d_in[9];
    const float* RW       = (const float*)d_in[10];
    const float* bias     = (const float*)d_in[11];
    const float* wgp      = (const float*)d_in[12];

    float* out = (float*)d_out;
    char* ws = (char*)d_ws;
    float* invm = (float*)(ws + WS_INVM);
    float* hT   = (float*)(ws + WS_HT);
    unsigned long long* colmin = (unsigned long long*)(ws + WS_COLMIN);
    float* minv = (float*)(ws + WS_MINV);
    int* count  = (int*)(ws + WS_COUNT);
    float* part = (float*)(ws + WS_PART);
    const int use_part = (ws_size >= (size_t)WS_PART + PART_BYTES) ? 1 : 0;

    if (!use_part)
        hipMemsetAsync(out + OFF_READ, 0, BATCH * UNITS * sizeof(float), stream);
    hipMemsetAsync(colmin, 0xFF, BATCH * sizeof(unsigned long long), stream);
    hipMemsetAsync(count, 0, MEM * sizeof(int), stream);

    k_lstm<<<BATCH / 4, 512, 0, stream>>>(inp, r_tm1, h_tm1, c_tm1, W, RW, bias, out, hT);
    k_mnorm<<<MEM / 16, 256, 0, stream>>>(m_tm1, invm);
    k_cos_softmax<<<MEM / MT, 128, 0, stream>>>(m_tm1, invm, hT, cwr_tm1, cwlu_tm1,
                                                cwu_tm1, wgp, out, colmin);
    k_decode<<<1, BATCH, 0, stream>>>(colmin, minv, count);
    k_wlu<<<(MEM * BATCH / 4) / 256, 256, 0, stream>>>(out + OFF_CWU, minv, out + OFF_CWLU);
    k_memory<<<MEM / 64, 256, 0, stream>>>(out + OFF_CWW, out + OFF_H, m_tm1, count,
                                           out + OFF_MEMORY);
    k_read<<<64 * 8, 256, 0, stream>>>(out + OFF_CWR, m_tm1,
                                       use_part ? part : (out + OFF_READ), use_part);
    if (use_part)
        k_reduce<<<(BATCH * UNITS) / 256, 256, 0, stream>>>(part, out + OFF_READ);
}

// Round 3
// 477.811 us; speedup vs baseline: 1.3507x; 1.0324x over previous
//
#include <hip/hip_runtime.h>
#include <math.h>

#define MEM 32768
#define UNITS 128
#define BATCH 256
#define IN_DIM 512
#define ZDIM 512      // 4*UNITS
#define CI_DIM 768    // IN_DIM + UNITS(r) + UNITS(h)

// ---- d_out offsets (floats), reference return order ----
#define OFF_READ   0
#define OFF_MEMORY (OFF_READ + BATCH*UNITS)        // 32768
#define OFF_CWU    (OFF_MEMORY + MEM*UNITS)        // 4227072
#define OFF_CWLU   (OFF_CWU + MEM*BATCH)           // 12615680
#define OFF_CWR    (OFF_CWLU + MEM*BATCH)          // 21004288
#define OFF_CWW    (OFF_CWR + MEM*BATCH)           // 29392896
#define OFF_H      (OFF_CWW + MEM*BATCH)           // 37781504
#define OFF_C      (OFF_H + BATCH*UNITS)           // 37814272

// ---- ws offsets (bytes) ----
#define WS_HT     0                                // float[UNITS*BATCH] (scaled h^T)
#define WS_COLMIN (UNITS*BATCH*4)                  // u64[BATCH]
#define WS_MINV   (WS_COLMIN + BATCH*8)            // float[BATCH]
#define WS_COUNT  (WS_MINV + BATCH*4)              // int[MEM]
#define WS_BHI    (WS_COUNT + MEM*4)               // short8[16*256] swizzled B hi (64 KB)
#define WS_BLO    (WS_BHI + 65536)                 // short8[16*256] swizzled B lo (64 KB)
#define WS_PART   (512*1024)                       // float[64][BATCH][UNITS] split-K partials
#define PART_BYTES (64*BATCH*UNITS*4)              // 8 MB

typedef __attribute__((ext_vector_type(8))) short short8;
typedef __attribute__((ext_vector_type(4))) float f32x4;

__device__ __forceinline__ float sigf(float x) { return 1.0f / (1.0f + __expf(-x)); }
// bf16 round-to-nearest-even from f32 (bits as short)
__device__ __forceinline__ short bf16r(float x) {
    unsigned u = __float_as_uint(x);
    return (short)((u + 0x7fffu + ((u >> 16) & 1u)) >> 16);
}
__device__ __forceinline__ float bf16f(short h) {
    return __uint_as_float(((unsigned)(unsigned short)h) << 16);
}

// ------------------------------------------------------------------
// K1: LSTM cell (4 rows/block), h/c outputs, h-norm, scaled h^T to ws
// ------------------------------------------------------------------
__global__ __launch_bounds__(512) void k_lstm(
    const float* __restrict__ inp, const float* __restrict__ r_tm1,
    const float* __restrict__ h_tm1, const float* __restrict__ c_tm1,
    const float* __restrict__ W, const float* __restrict__ RW,
    const float* __restrict__ bias,
    float* __restrict__ out, float* __restrict__ hT)
{
    __shared__ float ci[4][CI_DIM];
    __shared__ float zl[4][ZDIM];
    __shared__ float part[8];
    const int t = threadIdx.x;
    const int row0 = blockIdx.x * 4;

    for (int i = t; i < 4 * CI_DIM; i += 512) {
        int r = i / CI_DIM, j = i - r * CI_DIM;
        int row = row0 + r;
        float v;
        if (j < IN_DIM)              v = inp[row * IN_DIM + j];
        else if (j < IN_DIM + UNITS) v = r_tm1[row * UNITS + (j - IN_DIM)];
        else                         v = h_tm1[row * UNITS + (j - IN_DIM - UNITS)];
        ci[r][j] = v;
    }
    __syncthreads();

    float b = bias[t];
    float z0 = b, z1 = b, z2 = b, z3 = b;
    for (int k4 = 0; k4 < (IN_DIM + UNITS) / 4; ++k4) {
        float w0 = W[(k4 * 4 + 0) * ZDIM + t];
        float w1 = W[(k4 * 4 + 1) * ZDIM + t];
        float w2 = W[(k4 * 4 + 2) * ZDIM + t];
        float w3 = W[(k4 * 4 + 3) * ZDIM + t];
        float4 a0 = *(const float4*)&ci[0][k4 * 4];
        float4 a1 = *(const float4*)&ci[1][k4 * 4];
        float4 a2 = *(const float4*)&ci[2][k4 * 4];
        float4 a3 = *(const float4*)&ci[3][k4 * 4];
        z0 += a0.x * w0 + a0.y * w1 + a0.z * w2 + a0.w * w3;
        z1 += a1.x * w0 + a1.y * w1 + a1.z * w2 + a1.w * w3;
        z2 += a2.x * w0 + a2.y * w1 + a2.z * w2 + a2.w * w3;
        z3 += a3.x * w0 + a3.y * w1 + a3.z * w2 + a3.w * w3;
    }
    for (int k4 = 0; k4 < UNITS / 4; ++k4) {
        float w0 = RW[(k4 * 4 + 0) * ZDIM + t];
        float w1 = RW[(k4 * 4 + 1) * ZDIM + t];
        float w2 = RW[(k4 * 4 + 2) * ZDIM + t];
        float w3 = RW[(k4 * 4 + 3) * ZDIM + t];
        const int base = IN_DIM + UNITS + k4 * 4;
        float4 a0 = *(const float4*)&ci[0][base];
        float4 a1 = *(const float4*)&ci[1][base];
        float4 a2 = *(const float4*)&ci[2][base];
        float4 a3 = *(const float4*)&ci[3][base];
        z0 += a0.x * w0 + a0.y * w1 + a0.z * w2 + a0.w * w3;
        z1 += a1.x * w0 + a1.y * w1 + a1.z * w2 + a1.w * w3;
        z2 += a2.x * w0 + a2.y * w1 + a2.z * w2 + a2.w * w3;
        z3 += a3.x * w0 + a3.y * w1 + a3.z * w2 + a3.w * w3;
    }
    zl[0][t] = z0; zl[1][t] = z1; zl[2][t] = z2; zl[3][t] = z3;
    __syncthreads();

    const int r = t >> 7, u = t & 127;
    const int row = row0 + r;
    float iv = zl[r][u], fv = zl[r][UNITS + u], gv = zl[r][2 * UNITS + u], ov = zl[r][3 * UNITS + u];
    float ig = sigf(iv), fg = sigf(fv), og = sigf(ov);
    float gt = tanhf(gv);
    float cn = fg * c_tm1[row * UNITS + u] + ig * gt;
    float hn = og * tanhf(cn);
    out[OFF_C + row * UNITS + u] = cn;
    out[OFF_H + row * UNITS + u] = hn;

    float s = hn * hn;
    for (int d = 1; d < 64; d <<= 1) s += __shfl_xor(s, d, 64);
    int wave = t >> 6;
    if ((t & 63) == 0) part[wave] = s;
    __syncthreads();
    float inv = rsqrtf(fmaxf(part[2 * r] + part[2 * r + 1], 1e-12f));
    hT[u * BATCH + row] = hn * inv;
}

// ------------------------------------------------------------------
// K2a: normalize m rows + write A operand (bf16 hi/lo) in MFMA-A swizzle.
// Block = one m_tile of 16 rows. Thread t: s=t>>6, L=t&63 ->
// element run: row = mt*16+(L&15), k = s*32+(L>>4)*8 + j (j=0..7).
// Out flat index (short8): mt*256 + t  (fully coalesced).
// ------------------------------------------------------------------
__global__ __launch_bounds__(256) void k_prep_m(
    const float* __restrict__ m, short8* __restrict__ Ahi, short8* __restrict__ Alo)
{
    __shared__ float part[16 * 17];
    const int t = threadIdx.x, mt = blockIdx.x;
    const int s = t >> 6, L = t & 63;
    const int row = mt * 16 + (L & 15);
    const int k0 = s * 32 + (L >> 4) * 8;
    float x[8];
    float4 v0 = *(const float4*)&m[row * UNITS + k0];
    float4 v1 = *(const float4*)&m[row * UNITS + k0 + 4];
    x[0] = v0.x; x[1] = v0.y; x[2] = v0.z; x[3] = v0.w;
    x[4] = v1.x; x[5] = v1.y; x[6] = v1.z; x[7] = v1.w;
    float ss = 0.f;
#pragma unroll
    for (int j = 0; j < 8; ++j) ss += x[j] * x[j];
    part[(L & 15) * 17 + s * 4 + (L >> 4)] = ss;
    __syncthreads();
    float tot = 0.f;
#pragma unroll
    for (int i = 0; i < 16; ++i) tot += part[(L & 15) * 17 + i];
    float inv = rsqrtf(fmaxf(tot, 1e-12f));
    short8 hi, lo;
#pragma unroll
    for (int j = 0; j < 8; ++j) {
        float xv = x[j] * inv;
        short hb = bf16r(xv);
        hi[j] = hb;
        lo[j] = bf16r(xv - bf16f(hb));
    }
    Ahi[mt * 256 + t] = hi;
    Alo[mt * 256 + t] = lo;
}

// ------------------------------------------------------------------
// K2b: swizzle normalized h^T (f32 [u][b]) into MFMA-B layout (bf16 hi/lo).
// Block = one b_tile of 16. Thread t: s=t>>6, L=t&63 ->
// element run: k = s*32+(L>>4)*8+j, b = bt*16+(L&15). Out: bt*256 + t.
// ------------------------------------------------------------------
__global__ __launch_bounds__(256) void k_hswz(
    const float* __restrict__ hT, short8* __restrict__ Bhi, short8* __restrict__ Blo)
{
    const int t = threadIdx.x, bt = blockIdx.x;
    const int s = t >> 6, L = t & 63;
    const int b = bt * 16 + (L & 15);
    const int k0 = s * 32 + (L >> 4) * 8;
    short8 hi, lo;
#pragma unroll
    for (int j = 0; j < 8; ++j) {
        float x = hT[(k0 + j) * BATCH + b];
        short hb = bf16r(x);
        hi[j] = hb;
        lo[j] = bf16r(x - bf16f(hb));
    }
    Bhi[bt * 256 + t] = hi;
    Blo[bt * 256 + t] = lo;
}

// ------------------------------------------------------------------
// K3 v2: cos (MFMA bf16 hi/lo split) + softmax + c_wr/c_ww/c_wu + col-min.
// 32 m-rows/block, 256 threads (4 waves). Wave w: m_tile (w>>1), b-half (w&1).
// Per wave: 8 b-tiles x 4 K-steps x 3 split MFMAs. C -> LDS -> phase 2.
// ------------------------------------------------------------------
__global__ __launch_bounds__(256) void k_cos_softmax(
    const short8* __restrict__ Ahi, const short8* __restrict__ Alo,
    const short8* __restrict__ Bhi, const short8* __restrict__ Blo,
    const float* __restrict__ cwr_tm1, const float* __restrict__ cwlu_tm1,
    const float* __restrict__ cwu_tm1, const float* __restrict__ wgp,
    float* __restrict__ out, unsigned long long* __restrict__ colmin)
{
    __shared__ float cosLS[32 * 260];          // 33280 B; reused for wave minima
    const int t = threadIdx.x;
    const int w = t >> 6, L = t & 63;
    const int m0 = blockIdx.x * 32;
    const int mt = blockIdx.x * 2 + (w >> 1);
    const int bh = w & 1;

    short8 ah[4], al[4];
#pragma unroll
    for (int s = 0; s < 4; ++s) {
        ah[s] = Ahi[(mt * 4 + s) * 64 + L];
        al[s] = Alo[(mt * 4 + s) * 64 + L];
    }

    const int rbase = (w >> 1) * 16 + (L >> 4) * 4;
#pragma unroll
    for (int i = 0; i < 8; ++i) {
        const int bt = bh * 8 + i;
        f32x4 acc = {0.f, 0.f, 0.f, 0.f};
#pragma unroll
        for (int s = 0; s < 4; ++s) {
            short8 bhv = Bhi[(bt * 4 + s) * 64 + L];
            short8 blv = Blo[(bt * 4 + s) * 64 + L];
            acc = __builtin_amdgcn_mfma_f32_16x16x32_bf16(ah[s], bhv, acc, 0, 0, 0);
            acc = __builtin_amdgcn_mfma_f32_16x16x32_bf16(ah[s], blv, acc, 0, 0, 0);
            acc = __builtin_amdgcn_mfma_f32_16x16x32_bf16(al[s], bhv, acc, 0, 0, 0);
        }
        const int col = bt * 16 + (L & 15);
#pragma unroll
        for (int r = 0; r < 4; ++r) cosLS[(rbase + r) * 260 + col] = acc[r];
    }
    __syncthreads();

    // ---- phase 2: per-row softmax + ew outputs; wave w owns rows w*8..w*8+7
    const float wg = sigf(wgp[0]);
    const float wgc = 1.0f - wg;
    unsigned long long mk0 = ~0ULL, mk1 = ~0ULL, mk2 = ~0ULL, mk3 = ~0ULL;

#pragma unroll
    for (int i = 0; i < 8; ++i) {
        int ml = w * 8 + i;
        int row = m0 + ml;
        float4 v = *(const float4*)&cosLS[ml * 260 + L * 4];
        float mx = fmaxf(fmaxf(v.x, v.y), fmaxf(v.z, v.w));
        for (int d = 1; d < 64; d <<= 1) mx = fmaxf(mx, __shfl_xor(mx, d, 64));
        float4 e;
        e.x = __expf(v.x - mx); e.y = __expf(v.y - mx);
        e.z = __expf(v.z - mx); e.w = __expf(v.w - mx);
        float s = e.x + e.y + e.z + e.w;
        for (int d = 1; d < 64; d <<= 1) s += __shfl_xor(s, d, 64);
        float is = 1.0f / s;
        float4 wr; wr.x = e.x * is; wr.y = e.y * is; wr.z = e.z * is; wr.w = e.w * is;
        *(float4*)&out[OFF_CWR + row * BATCH + L * 4] = wr;

        float4 pr = *(const float4*)&cwr_tm1[row * BATCH + L * 4];
        float4 pl = *(const float4*)&cwlu_tm1[row * BATCH + L * 4];
        float4 ww;
        ww.x = wg * pr.x + wgc + pl.x; ww.y = wg * pr.y + wgc + pl.y;
        ww.z = wg * pr.z + wgc + pl.z; ww.w = wg * pr.w + wgc + pl.w;
        *(float4*)&out[OFF_CWW + row * BATCH + L * 4] = ww;

        float4 pu = *(const float4*)&cwu_tm1[row * BATCH + L * 4];
        float4 wu;
        wu.x = 0.95f * pu.x + wr.x + ww.x; wu.y = 0.95f * pu.y + wr.y + ww.y;
        wu.z = 0.95f * pu.z + wr.z + ww.z; wu.w = 0.95f * pu.w + wr.w + ww.w;
        *(float4*)&out[OFF_CWU + row * BATCH + L * 4] = wu;

        // pack (bits<<32)|(MEM-1-row): min-key => min value, largest index on ties
        unsigned idxc = (unsigned)(MEM - 1 - row);
        unsigned long long k;
        k = ((unsigned long long)__float_as_uint(wu.x) << 32) | idxc; if (k < mk0) mk0 = k;
        k = ((unsigned long long)__float_as_uint(wu.y) << 32) | idxc; if (k < mk1) mk1 = k;
        k = ((unsigned long long)__float_as_uint(wu.z) << 32) | idxc; if (k < mk2) mk2 = k;
        k = ((unsigned long long)__float_as_uint(wu.w) << 32) | idxc; if (k < mk3) mk3 = k;
    }
    __syncthreads();
    unsigned long long* wmin = (unsigned long long*)cosLS;
    wmin[w * BATCH + L * 4 + 0] = mk0;
    wmin[w * BATCH + L * 4 + 1] = mk1;
    wmin[w * BATCH + L * 4 + 2] = mk2;
    wmin[w * BATCH + L * 4 + 3] = mk3;
    __syncthreads();
    {
        unsigned long long a = wmin[t];
        unsigned long long b2 = wmin[BATCH + t];
        unsigned long long c2 = wmin[2 * BATCH + t];
        unsigned long long d2 = wmin[3 * BATCH + t];
        unsigned long long k = a < b2 ? a : b2;
        if (c2 < k) k = c2;
        if (d2 < k) k = d2;
        if (k < colmin[t]) atomicMin(&colmin[t], k);   // peek to skip most atomics
    }
}

// ------------------------------------------------------------------
// K4: decode column minima -> minv + argmin counts
// ------------------------------------------------------------------
__global__ void k_decode(const unsigned long long* __restrict__ colmin,
                         float* __restrict__ minv, int* __restrict__ count)
{
    int t = threadIdx.x;
    unsigned long long k = colmin[t];
    minv[t] = __uint_as_float((unsigned)(k >> 32));
    int idx = MEM - 1 - (int)(unsigned)(k & 0xffffffffu);
    atomicAdd(&count[idx], 1);
}

// ------------------------------------------------------------------
// K5: c_wlu = (c_wu <= minv[b])
// ------------------------------------------------------------------
__global__ __launch_bounds__(256) void k_wlu(const float* __restrict__ cwu,
                                             const float* __restrict__ minv,
                                             float* __restrict__ wlu)
{
    int i = blockIdx.x * 256 + threadIdx.x;   // float4 index
    float4 v = *(const float4*)&cwu[i * 4];
    float4 mv = *(const float4*)&minv[(i & 63) * 4];
    float4 r;
    r.x = (v.x <= mv.x) ? 1.0f : 0.0f;
    r.y = (v.y <= mv.y) ? 1.0f : 0.0f;
    r.z = (v.z <= mv.z) ? 1.0f : 0.0f;
    r.w = (v.w <= mv.w) ? 1.0f : 0.0f;
    *(float4*)&wlu[i * 4] = r;
}

// ------------------------------------------------------------------
// K6: memory = c_ww @ h + (BATCH - count[m]) * m_tm1  (LDS-tiled GEMM)
// ------------------------------------------------------------------
__global__ __launch_bounds__(256) void k_memory(
    const float* __restrict__ cww, const float* __restrict__ h,
    const float* __restrict__ m, const int* __restrict__ count,
    float* __restrict__ mem_out)
{
    __shared__ float Als[32 * 68];
    __shared__ float Bls[32 * 128];
    const int t = threadIdx.x;
    const int m0 = blockIdx.x * 64;
    const int u4 = (t & 31) * 4;     // u offset
    const int mg = t >> 5;           // 0..7, owns m-rows mg*8..mg*8+7
    float4 acc[8];
#pragma unroll
    for (int i = 0; i < 8; ++i) { acc[i].x = 0.f; acc[i].y = 0.f; acc[i].z = 0.f; acc[i].w = 0.f; }

    for (int b0 = 0; b0 < BATCH; b0 += 32) {
#pragma unroll
        for (int ii = 0; ii < 2; ++ii) {
            int i = t + ii * 256;
            int ml = i >> 3, bb4 = (i & 7) * 4;
            float4 v = *(const float4*)&cww[(m0 + ml) * BATCH + b0 + bb4];
            Als[(bb4 + 0) * 68 + ml] = v.x;
            Als[(bb4 + 1) * 68 + ml] = v.y;
            Als[(bb4 + 2) * 68 + ml] = v.z;
            Als[(bb4 + 3) * 68 + ml] = v.w;
        }
#pragma unroll
        for (int ii = 0; ii < 4; ++ii) {
            int i = t + ii * 256;
            int bb = i >> 5, uu = (i & 31) * 4;
            *(float4*)&Bls[bb * 128 + uu] = *(const float4*)&h[(b0 + bb) * UNITS + uu];
        }
        __syncthreads();
#pragma unroll 8
        for (int bb = 0; bb < 32; ++bb) {
            float4 bv = *(const float4*)&Bls[bb * 128 + u4];
            float4 av0 = *(const float4*)&Als[bb * 68 + mg * 8];
            float4 av1 = *(const float4*)&Als[bb * 68 + mg * 8 + 4];
            acc[0].x += av0.x * bv.x; acc[0].y += av0.x * bv.y; acc[0].z += av0.x * bv.z; acc[0].w += av0.x * bv.w;
            acc[1].x += av0.y * bv.x; acc[1].y += av0.y * bv.y; acc[1].z += av0.y * bv.z; acc[1].w += av0.y * bv.w;
            acc[2].x += av0.z * bv.x; acc[2].y += av0.z * bv.y; acc[2].z += av0.z * bv.z; acc[2].w += av0.z * bv.w;
            acc[3].x += av0.w * bv.x; acc[3].y += av0.w * bv.y; acc[3].z += av0.w * bv.z; acc[3].w += av0.w * bv.w;
            acc[4].x += av1.x * bv.x; acc[4].y += av1.x * bv.y; acc[4].z += av1.x * bv.z; acc[4].w += av1.x * bv.w;
            acc[5].x += av1.y * bv.x; acc[5].y += av1.y * bv.y; acc[5].z += av1.y * bv.z; acc[5].w += av1.y * bv.w;
            acc[6].x += av1.z * bv.x; acc[6].y += av1.z * bv.y; acc[6].z += av1.z * bv.z; acc[6].w += av1.z * bv.w;
            acc[7].x += av1.w * bv.x; acc[7].y += av1.w * bv.y; acc[7].z += av1.w * bv.z; acc[7].w += av1.w * bv.w;
        }
        __syncthreads();
    }

#pragma unroll
    for (int i = 0; i < 8; ++i) {
        int row = m0 + mg * 8 + i;
        float sc = (float)(BATCH - count[row]);
        float4 mv = *(const float4*)&m[row * UNITS + u4];
        float4 o;
        o.x = acc[i].x + sc * mv.x;
        o.y = acc[i].y + sc * mv.y;
        o.z = acc[i].z + sc * mv.z;
        o.w = acc[i].w + sc * mv.w;
        *(float4*)&mem_out[row * UNITS + u4] = o;
    }
}

// ------------------------------------------------------------------
// K7: read = c_wr^T @ m_tm1, LDS-tiled split-K GEMM
// ------------------------------------------------------------------
__global__ __launch_bounds__(256) void k_read(
    const float* __restrict__ cwr, const float* __restrict__ m,
    float* __restrict__ dst, int use_part)
{
    __shared__ float Als[32 * 36];    // [mm][b] stride 36 (16B aligned)
    __shared__ float Bls[32 * 128];   // [mm][u]
    const int t = threadIdx.x;
    const int c  = blockIdx.x >> 3;
    const int b0 = (blockIdx.x & 7) * 32;
    const int k0 = c * 512;
    const int u4 = (t & 31) * 4;
    const int bg = t >> 5;
    float4 a0, a1, a2, a3;
    a0.x=0;a0.y=0;a0.z=0;a0.w=0; a1=a0; a2=a0; a3=a0;

    for (int mc = 0; mc < 16; ++mc) {
        const int kb = k0 + mc * 32;
        {
            int row = t >> 3, j4 = (t & 7) * 4;
            float4 v = *(const float4*)&cwr[(kb + row) * BATCH + b0 + j4];
            *(float4*)&Als[row * 36 + j4] = v;
        }
#pragma unroll
        for (int ii = 0; ii < 4; ++ii) {
            int i = t + ii * 256;
            int bb = i >> 5, uu = (i & 31) * 4;
            *(float4*)&Bls[bb * 128 + uu] = *(const float4*)&m[(kb + bb) * UNITS + uu];
        }
        __syncthreads();
#pragma unroll 8
        for (int mm = 0; mm < 32; ++mm) {
            float4 av = *(const float4*)&Als[mm * 36 + bg * 4];
            float4 bv = *(const float4*)&Bls[mm * 128 + u4];
            a0.x += av.x * bv.x; a0.y += av.x * bv.y; a0.z += av.x * bv.z; a0.w += av.x * bv.w;
            a1.x += av.y * bv.x; a1.y += av.y * bv.y; a1.z += av.y * bv.z; a1.w += av.y * bv.w;
            a2.x += av.z * bv.x; a2.y += av.z * bv.y; a2.z += av.z * bv.z; a2.w += av.z * bv.w;
            a3.x += av.w * bv.x; a3.y += av.w * bv.y; a3.z += av.w * bv.z; a3.w += av.w * bv.w;
        }
        __syncthreads();
    }

    const int b = b0 + bg * 4;
    if (use_part) {
        float* p = dst + (size_t)c * (BATCH * UNITS);
        *(float4*)&p[(b + 0) * UNITS + u4] = a0;
        *(float4*)&p[(b + 1) * UNITS + u4] = a1;
        *(float4*)&p[(b + 2) * UNITS + u4] = a2;
        *(float4*)&p[(b + 3) * UNITS + u4] = a3;
    } else {
        atomicAdd(&dst[(b + 0) * UNITS + u4 + 0], a0.x); atomicAdd(&dst[(b + 0) * UNITS + u4 + 1], a0.y);
        atomicAdd(&dst[(b + 0) * UNITS + u4 + 2], a0.z); atomicAdd(&dst[(b + 0) * UNITS + u4 + 3], a0.w);
        atomicAdd(&dst[(b + 1) * UNITS + u4 + 0], a1.x); atomicAdd(&dst[(b + 1) * UNITS + u4 + 1], a1.y);
        atomicAdd(&dst[(b + 1) * UNITS + u4 + 2], a1.z); atomicAdd(&dst[(b + 1) * UNITS + u4 + 3], a1.w);
        atomicAdd(&dst[(b + 2) * UNITS + u4 + 0], a2.x); atomicAdd(&dst[(b + 2) * UNITS + u4 + 1], a2.y);
        atomicAdd(&dst[(b + 2) * UNITS + u4 + 2], a2.z); atomicAdd(&dst[(b + 2) * UNITS + u4 + 3], a2.w);
        atomicAdd(&dst[(b + 3) * UNITS + u4 + 0], a3.x); atomicAdd(&dst[(b + 3) * UNITS + u4 + 1], a3.y);
        atomicAdd(&dst[(b + 3) * UNITS + u4 + 2], a3.z); atomicAdd(&dst[(b + 3) * UNITS + u4 + 3], a3.w);
    }
}

// ------------------------------------------------------------------
// K8: reduce split-K partials -> read
// ------------------------------------------------------------------
__global__ __launch_bounds__(256) void k_reduce(const float* __restrict__ part,
                                                float* __restrict__ out)
{
    int i = blockIdx.x * 256 + threadIdx.x;     // 0 .. BATCH*UNITS
    float s = 0.f;
#pragma unroll
    for (int c = 0; c < 64; ++c) s += part[c * (BATCH * UNITS) + i];
    out[i] = s;
}

// ------------------------------------------------------------------
extern "C" void kernel_launch(void* const* d_in, const int* in_sizes, int n_in,
                              void* d_out, int out_size, void* d_ws, size_t ws_size,
                              hipStream_t stream)
{
    (void)in_sizes; (void)n_in; (void)out_size;
    const float* inp      = (const float*)d_in[0];
    const float* r_tm1    = (const float*)d_in[1];
    const float* m_tm1    = (const float*)d_in[2];
    const float* cwu_tm1  = (const float*)d_in[3];
    const float* cwlu_tm1 = (const float*)d_in[4];
    const float* cwr_tm1  = (const float*)d_in[5];
    // d_in[6] = c_ww_tm1: unused by the reference
    const float* h_tm1    = (const float*)d_in[7];
    const float* c_tm1    = (const float*)d_in[8];
    const float* W        = (const float*)d_in[9];
    const float* RW       = (const float*)d_in[10];
    const float* bias     = (const float*)d_in[11];
    const float* wgp      = (const float*)d_in[12];

    float* out = (float*)d_out;
    char* ws = (char*)d_ws;
    float* hT   = (float*)(ws + WS_HT);
    unsigned long long* colmin = (unsigned long long*)(ws + WS_COLMIN);
    float* minv = (float*)(ws + WS_MINV);
    int* count  = (int*)(ws + WS_COUNT);
    short8* Bhi = (short8*)(ws + WS_BHI);
    short8* Blo = (short8*)(ws + WS_BLO);
    float* part = (float*)(ws + WS_PART);
    const int use_part = (ws_size >= (size_t)WS_PART + PART_BYTES) ? 1 : 0;

    // A operand (swizzled bf16 hi/lo, 8 MB each) lives in the CWLU output
    // region, which is not written until k_wlu (after k_cos consumed it).
    short8* Ahi = (short8*)(out + OFF_CWLU);
    short8* Alo = Ahi + (MEM * UNITS / 8);

    if (!use_part)
        hipMemsetAsync(out + OFF_READ, 0, BATCH * UNITS * sizeof(float), stream);
    hipMemsetAsync(colmin, 0xFF, BATCH * sizeof(unsigned long long), stream);
    hipMemsetAsync(count, 0, MEM * sizeof(int), stream);

    k_lstm<<<BATCH / 4, 512, 0, stream>>>(inp, r_tm1, h_tm1, c_tm1, W, RW, bias, out, hT);
    k_hswz<<<16, 256, 0, stream>>>(hT, Bhi, Blo);
    k_prep_m<<<MEM / 16, 256, 0, stream>>>(m_tm1, Ahi, Alo);
    k_cos_softmax<<<MEM / 32, 256, 0, stream>>>(Ahi, Alo, Bhi, Blo,
                                                cwr_tm1, cwlu_tm1, cwu_tm1, wgp,
                                                out, colmin);
    k_decode<<<1, BATCH, 0, stream>>>(colmin, minv, count);
    k_wlu<<<(MEM * BATCH / 4) / 256, 256, 0, stream>>>(out + OFF_CWU, minv, out + OFF_CWLU);
    k_memory<<<MEM / 64, 256, 0, stream>>>(out + OFF_CWW, out + OFF_H, m_tm1, count,
                                           out + OFF_MEMORY);
    k_read<<<64 * 8, 256, 0, stream>>>(out + OFF_CWR, m_tm1,
                                       use_part ? part : (out + OFF_READ), use_part);
    if (use_part)
        k_reduce<<<(BATCH * UNITS) / 256, 256, 0, stream>>>(part, out + OFF_READ);
}